// Round 1
// baseline (7290.546 us; speedup 1.0000x reference)
//
#include <hip/hip_runtime.h>
#include <hip/hip_bf16.h>
#include <math.h>

#define Bb   128
#define Ss   512
#define Ff   64
#define Hh   512
#define NGc  2053          // 4*H + 5
#define Kk   576           // F + H
#define NWG  64
#define BST  584           // padded k-stride (shorts) for LDS weights

// workspace layout (bytes)
#define OFF_HB    256                      // 2 x B*H bf16 ping-pong (131072 each)
#define OFF_HFIN  262400                   // B*H fp32
#define OFF_CFIN  524544                   // 5 x B*H fp32
#define OFF_R1    1835264                  // 128x256 fp32
#define OFF_R2    1966336                  // 128x128 fp32
#define OFF_Y1    2031872                  // 5 x 128x256 fp32

typedef __attribute__((ext_vector_type(8))) short short8;
typedef __attribute__((ext_vector_type(4))) float f32x4;

__device__ __forceinline__ short f2bf(float f) {
    union { float f; unsigned u; } v; v.f = f;
    unsigned r = v.u + 0x7fffu + ((v.u >> 16) & 1u);
    return (short)(r >> 16);
}

__device__ __forceinline__ void gbar(unsigned* cnt, unsigned* gen, unsigned target) {
    __syncthreads();
    if (threadIdx.x == 0) {
        __threadfence();
        if (__hip_atomic_fetch_add(cnt, 1u, __ATOMIC_ACQ_REL, __HIP_MEMORY_SCOPE_AGENT)
            == (unsigned)(NWG - 1)) {
            __hip_atomic_store(cnt, 0u, __ATOMIC_RELAXED, __HIP_MEMORY_SCOPE_AGENT);
            __hip_atomic_store(gen, target, __ATOMIC_RELEASE, __HIP_MEMORY_SCOPE_AGENT);
        } else {
            while (__hip_atomic_load(gen, __ATOMIC_ACQUIRE, __HIP_MEMORY_SCOPE_AGENT) < target) {
                __builtin_amdgcn_s_sleep(1);
            }
        }
        __threadfence();
    }
    __syncthreads();
}

__global__ __launch_bounds__(256, 1) void mclstm_main(
    const float* __restrict__ xin, const float* __restrict__ Wm,
    const float* __restrict__ Um,  const float* __restrict__ k1,
    const float* __restrict__ bias, const float* __restrict__ bias1,
    float* __restrict__ out, unsigned char* __restrict__ ws)
{
    __shared__ __align__(16) short sB[48 * BST];   // 56 KB: Bt[n][k] bf16
    __shared__ float sD[128 * 8];                  // d-gate dump / d values

    const int tid  = threadIdx.x;
    const int wg   = blockIdx.x;
    const int lane = tid & 63;
    const int wave = tid >> 6;
    const int j0   = wg * 8;

    unsigned* bar  = (unsigned*)ws;                 // [0]=cnt [1]=gen (memset 0)
    short*    hbuf = (short*)(ws + OFF_HB);
    float*    hfin = (float*)(ws + OFF_HFIN);
    float*    cfin = (float*)(ws + OFF_CFIN);

    // ---- stage weights into LDS: sB[n*BST + k], n in [0,48) ----
    for (int e = tid; e < 48 * Kk; e += 256) {
        int n = e % 48, k = e / 48;
        int col;
        if (n < 32) col = (n >> 3) * Hh + j0 + (n & 7);
        else        col = (n - 32 < 5) ? (4 * Hh + (n - 32)) : -1;
        float v = 0.f;
        if (col >= 0) v = (k < Ff) ? Wm[(size_t)k * NGc + col]
                                   : Um[(size_t)(k - Ff) * NGc + col];
        sB[n * BST + k] = f2bf(v);
    }

    // bias for accumulator init (per ntile, col = lane&15)
    float biasreg[3];
    {
        int nn = lane & 15;
        for (int nt = 0; nt < 3; ++nt) {
            int n = nt * 16 + nn;
            int col;
            if (n < 32) col = (n >> 3) * Hh + j0 + (n & 7);
            else        col = (n - 32 < 5) ? (4 * Hh + (n - 32)) : -1;
            biasreg[nt] = (col >= 0) ? bias[col] : 0.f;
        }
    }

    // per-lane elementwise constants (lane owns hidden unit u = lane&7)
    const int  u   = lane & 7;
    const bool low = (lane & 15) < 8;
    const float s1v = bias1[j0 + u];
    const float s2v = bias1[Hh + j0 + u];
    float kv[5];
#pragma unroll
    for (int g = 0; g < 5; ++g) kv[g] = k1[g * Hh + j0 + u];
    float cp[2][2] = {{0.f, 0.f}, {0.f, 0.f}};      // c state for lane's 4 (r,u)

    const int col16 = lane & 15;
    const int kgrp  = (lane >> 4) * 8;
    const int row0  = (wave * 2 + 0) * 16 + col16;
    const int row1  = (wave * 2 + 1) * 16 + col16;

    __syncthreads();

    for (int t = 0; t < Ss; ++t) {
        const short* hcur  = hbuf + (size_t)(t & 1) * (Bb * Hh);
        short*       hnext = hbuf + (size_t)((t + 1) & 1) * (Bb * Hh);

        f32x4 acc[3][2];
#pragma unroll
        for (int nt = 0; nt < 3; ++nt)
#pragma unroll
            for (int mt = 0; mt < 2; ++mt) {
                f32x4 z = {biasreg[nt], biasreg[nt], biasreg[nt], biasreg[nt]};
                acc[nt][mt] = z;
            }

        // ---- K part 1: x_t (k = 0..63) ----
#pragma unroll
        for (int k0 = 0; k0 < 2; ++k0) {
            int kb = k0 * 32 + kgrp;
            short8 a0, a1;
            {
                const float* p = xin + ((size_t)row0 * Ss + t) * Ff + kb;
                f32x4 f0 = *(const f32x4*)(p);
                f32x4 f1 = *(const f32x4*)(p + 4);
                a0[0]=f2bf(f0[0]); a0[1]=f2bf(f0[1]); a0[2]=f2bf(f0[2]); a0[3]=f2bf(f0[3]);
                a0[4]=f2bf(f1[0]); a0[5]=f2bf(f1[1]); a0[6]=f2bf(f1[2]); a0[7]=f2bf(f1[3]);
            }
            {
                const float* p = xin + ((size_t)row1 * Ss + t) * Ff + kb;
                f32x4 f0 = *(const f32x4*)(p);
                f32x4 f1 = *(const f32x4*)(p + 4);
                a1[0]=f2bf(f0[0]); a1[1]=f2bf(f0[1]); a1[2]=f2bf(f0[2]); a1[3]=f2bf(f0[3]);
                a1[4]=f2bf(f1[0]); a1[5]=f2bf(f1[1]); a1[6]=f2bf(f1[2]); a1[7]=f2bf(f1[3]);
            }
            int kbB = k0 * 32 + kgrp;
#pragma unroll
            for (int nt = 0; nt < 3; ++nt) {
                short8 b = *(const short8*)(sB + (nt * 16 + col16) * BST + kbB);
                acc[nt][0] = __builtin_amdgcn_mfma_f32_16x16x32_bf16(a0, b, acc[nt][0], 0, 0, 0);
                acc[nt][1] = __builtin_amdgcn_mfma_f32_16x16x32_bf16(a1, b, acc[nt][1], 0, 0, 0);
            }
        }
        // ---- K part 2: h (k = 64..575) ----
#pragma unroll 4
        for (int k0 = 2; k0 < 18; ++k0) {
            int kb = k0 * 32 + kgrp;
            short8 a0 = *(const short8*)(hcur + (size_t)row0 * Hh + (kb - 64));
            short8 a1 = *(const short8*)(hcur + (size_t)row1 * Hh + (kb - 64));
#pragma unroll
            for (int nt = 0; nt < 3; ++nt) {
                short8 b = *(const short8*)(sB + (nt * 16 + col16) * BST + kb);
                acc[nt][0] = __builtin_amdgcn_mfma_f32_16x16x32_bf16(a0, b, acc[nt][0], 0, 0, 0);
                acc[nt][1] = __builtin_amdgcn_mfma_f32_16x16x32_bf16(a1, b, acc[nt][1], 0, 0, 0);
            }
        }

        // ---- d gate: dump cols 0..4, softmax(tanh(.)) per row ----
        if (col16 < 5) {
#pragma unroll
            for (int mt = 0; mt < 2; ++mt)
#pragma unroll
                for (int j = 0; j < 4; ++j)
                    sD[((wave * 2 + mt) * 16 + (lane >> 4) * 4 + j) * 8 + col16] = acc[2][mt][j];
        }
        __syncthreads();
        if (tid < 128) {
            int r = tid;
            float v[5], mx = -1e30f;
#pragma unroll
            for (int c = 0; c < 5; ++c) { v[c] = tanhf(sD[r * 8 + c]); mx = fmaxf(mx, v[c]); }
            float s = 0.f;
#pragma unroll
            for (int c = 0; c < 5; ++c) { v[c] = __expf(v[c] - mx); s += v[c]; }
            float inv = 1.f / s;
#pragma unroll
            for (int c = 0; c < 5; ++c) sD[r * 8 + c] = v[c] * inv;
            if (t == Ss - 1 && wg == 0) {
#pragma unroll
                for (int c = 0; c < 5; ++c) out[1408 + r * 5 + c] = v[c] * inv;
            }
        }
        __syncthreads();

        // ---- cell update (C-layout in-register; shfl_xor(8) pairs i/f and g/o) ----
#pragma unroll
        for (int mt = 0; mt < 2; ++mt) {
            float o0[4], o1[4], p0[4], p1[4];
#pragma unroll
            for (int j = 0; j < 4; ++j) {
                o0[j] = acc[0][mt][j]; o1[j] = acc[1][mt][j];
                p0[j] = __shfl_xor(o0[j], 8); p1[j] = __shfl_xor(o1[j], 8);
            }
            int rb = (wave * 2 + mt) * 16 + (lane >> 4) * 4;
#pragma unroll
            for (int jj = 0; jj < 2; ++jj) {
                int j = low ? jj : (2 + jj);
                float gi = low ? o0[j] : p0[j];
                float gf = low ? p0[j] : o0[j];
                float gg = low ? o1[j] : p1[j];
                float go = low ? p1[j] : o1[j];
                int r = rb + j;
                float i_ = 1.f / (1.f + __expf(-gi));
                float f_ = 1.f / (1.f + __expf(-gf));
                float g_ = tanhf(gg);
                float o_ = 1.f / (1.f + __expf(-go));
                float c1v = tanhf(g_);
                float c5v = cp[mt][jj];
                float c3v = f_ * c5v + i_ * g_;
                float c2v = s2v * c3v + (1.f - s2v) * c1v;
                float c4v = s1v * c3v + (1.f - s1v) * c5v;
                const float* dr = sD + r * 8;
                float cn = dr[0] * kv[0] * c1v + dr[1] * kv[1] * c2v + dr[2] * kv[2] * c3v
                         + dr[3] * kv[3] * c4v + dr[4] * kv[4] * c5v;
                float hn = o_ * tanhf(cn);
                cp[mt][jj] = cn;
                size_t off = (size_t)r * Hh + j0 + u;
                hnext[off] = f2bf(hn);
                if (t == Ss - 1) {
                    hfin[off] = hn;
                    cfin[0 * Bb * Hh + off] = c1v;
                    cfin[1 * Bb * Hh + off] = c2v;
                    cfin[2 * Bb * Hh + off] = c3v;
                    cfin[3 * Bb * Hh + off] = c4v;
                    cfin[4 * Bb * Hh + off] = c5v;
                }
            }
        }
        if (t < Ss - 1) gbar(bar, bar + 1, (unsigned)(t + 1));
    }
}

// ---- heads: stage A: r1 = relu(h@rw1+rb1); y1[hd] = relu(c_hd@dw1+db1) ----
__global__ __launch_bounds__(256) void stageA(const unsigned char* __restrict__ ws,
    const float* __restrict__ rw1, const float* __restrict__ rb1,
    const float* __restrict__ dw1, const float* __restrict__ db1)
{
    __shared__ float sW[512 * 17];
    const int tid = threadIdx.x;
    const int blk = blockIdx.x;
    const float* hfin = (const float*)(ws + OFF_HFIN);
    const float* cfin = (const float*)(ws + OFF_CFIN);
    float* r1 = (float*)(ws + OFF_R1);
    float* y1 = (float*)(ws + OFF_Y1);

    const float* src; const float* Wm; const float* bv; float* dst; int cblk;
    if (blk < 16) { src = hfin; Wm = rw1; bv = rb1; dst = r1; cblk = blk; }
    else {
        int hd = (blk - 16) >> 4; cblk = (blk - 16) & 15;
        src = cfin + (size_t)hd * Bb * Hh; Wm = dw1; bv = db1;
        dst = y1 + (size_t)hd * Bb * 256;
    }
    for (int e = tid; e < 512 * 16; e += 256) {
        int k = e >> 4, c = e & 15;
        sW[k * 17 + c] = Wm[(size_t)k * 256 + cblk * 16 + c];
    }
    __syncthreads();
    for (int e = tid; e < 128 * 16; e += 256) {
        int r = e >> 4, c = e & 15;
        float a = bv[cblk * 16 + c];
        const float* sp = src + (size_t)r * 512;
        for (int k = 0; k < 512; k += 4) {
            f32x4 h4 = *(const f32x4*)(sp + k);
            a += h4[0] * sW[(k + 0) * 17 + c] + h4[1] * sW[(k + 1) * 17 + c]
               + h4[2] * sW[(k + 2) * 17 + c] + h4[3] * sW[(k + 3) * 17 + c];
        }
        dst[(size_t)r * 256 + cblk * 16 + c] = fmaxf(a, 0.f);
    }
}

// ---- stage B: r2 = relu(r1@rw2+rb2) ----
__global__ __launch_bounds__(256) void stageB(const unsigned char* __restrict__ ws,
    const float* __restrict__ rw2, const float* __restrict__ rb2)
{
    __shared__ float sW[256 * 17];
    const int tid = threadIdx.x;
    const int cblk = blockIdx.x;
    const float* r1 = (const float*)(ws + OFF_R1);
    float* r2 = (float*)(ws + OFF_R2);
    for (int e = tid; e < 256 * 16; e += 256) {
        int k = e >> 4, c = e & 15;
        sW[k * 17 + c] = rw2[(size_t)k * 128 + cblk * 16 + c];
    }
    __syncthreads();
    for (int e = tid; e < 128 * 16; e += 256) {
        int r = e >> 4, c = e & 15;
        float a = rb2[cblk * 16 + c];
        const float* sp = r1 + (size_t)r * 256;
        for (int k = 0; k < 256; k += 4) {
            f32x4 h4 = *(const f32x4*)(sp + k);
            a += h4[0] * sW[(k + 0) * 17 + c] + h4[1] * sW[(k + 1) * 17 + c]
               + h4[2] * sW[(k + 2) * 17 + c] + h4[3] * sW[(k + 3) * 17 + c];
        }
        r2[(size_t)r * 128 + cblk * 16 + c] = fmaxf(a, 0.f);
    }
}

// ---- stage C: BN + final projections + log_softmax ----
__global__ __launch_bounds__(256) void stageC(const unsigned char* __restrict__ ws,
    const float* __restrict__ rbng, const float* __restrict__ rbnb,
    const float* __restrict__ rw3,  const float* __restrict__ rb3,
    const float* __restrict__ dbng, const float* __restrict__ dbnb,
    const float* __restrict__ dw2,  const float* __restrict__ db2,
    float* __restrict__ out)
{
    __shared__ float sc[256], sh[256];
    const int tid = threadIdx.x;
    const int blk = blockIdx.x;
    const float* r2 = (const float*)(ws + OFF_R2);
    const float* y1 = (const float*)(ws + OFF_Y1);
    if (blk == 0) {
        if (tid < 128) {
            int c = tid; float s = 0.f, s2 = 0.f;
            for (int r = 0; r < 128; ++r) { float x = r2[r * 128 + c]; s += x; s2 += x * x; }
            float m = s * (1.f / 128.f), v = s2 * (1.f / 128.f) - m * m;
            float sca = rbng[c] * rsqrtf(v + 1e-5f);
            sc[c] = sca; sh[c] = rbnb[c] - m * sca;
        }
        __syncthreads();
        if (tid < 128) {
            int r = tid; float a = rb3[0];
            for (int c = 0; c < 128; ++c)
                a += (r2[r * 128 + c] * sc[c] + sh[c]) * rw3[c];
            out[r] = a;
        }
    } else {
        int hd = blk - 1;
        const float* y = y1 + (size_t)hd * 128 * 256;
        {
            int c = tid; float s = 0.f, s2 = 0.f;
            for (int r = 0; r < 128; ++r) { float x = y[r * 256 + c]; s += x; s2 += x * x; }
            float m = s * (1.f / 128.f), v = s2 * (1.f / 128.f) - m * m;
            float sca = dbng[c] * rsqrtf(v + 1e-5f);
            sc[c] = sca; sh[c] = dbnb[c] - m * sca;
        }
        __syncthreads();
        if (tid < 128) {
            int r = tid;
            float z0 = db2[0], z1 = db2[1];
            for (int c = 0; c < 256; ++c) {
                float yn = y[r * 256 + c] * sc[c] + sh[c];
                z0 += yn * dw2[c * 2 + 0];
                z1 += yn * dw2[c * 2 + 1];
            }
            float mx = fmaxf(z0, z1);
            float ls = mx + logf(__expf(z0 - mx) + __expf(z1 - mx));
            out[128 + hd * 256 + r * 2 + 0] = z0 - ls;
            out[128 + hd * 256 + r * 2 + 1] = z1 - ls;
        }
    }
}

extern "C" void kernel_launch(void* const* d_in, const int* in_sizes, int n_in,
                              void* d_out, int out_size, void* d_ws, size_t ws_size,
                              hipStream_t stream) {
    const float* x    = (const float*)d_in[0];
    const float* Wm   = (const float*)d_in[1];
    const float* Um   = (const float*)d_in[2];
    const float* k1   = (const float*)d_in[3];
    const float* bias = (const float*)d_in[4];
    const float* b1   = (const float*)d_in[5];
    const float* rw1  = (const float*)d_in[6];
    const float* rb1  = (const float*)d_in[7];
    const float* rw2  = (const float*)d_in[8];
    const float* rb2  = (const float*)d_in[9];
    const float* rbng = (const float*)d_in[10];
    const float* rbnb = (const float*)d_in[11];
    const float* rw3  = (const float*)d_in[12];
    const float* rb3  = (const float*)d_in[13];
    const float* dw1  = (const float*)d_in[14];
    const float* db1  = (const float*)d_in[15];
    const float* dbng = (const float*)d_in[16];
    const float* dbnb = (const float*)d_in[17];
    const float* dw2  = (const float*)d_in[18];
    const float* db2  = (const float*)d_in[19];
    (void)in_sizes; (void)n_in; (void)out_size; (void)ws_size;

    // zero barrier vars + h ping buffer 0
    hipMemsetAsync(d_ws, 0, OFF_HB + Bb * Hh * 2, stream);

    mclstm_main<<<NWG, 256, 0, stream>>>(x, Wm, Um, k1, bias, b1,
                                         (float*)d_out, (unsigned char*)d_ws);
    stageA<<<96, 256, 0, stream>>>((const unsigned char*)d_ws, rw1, rb1, dw1, db1);
    stageB<<<8, 256, 0, stream>>>((const unsigned char*)d_ws, rw2, rb2);
    stageC<<<6, 256, 0, stream>>>((const unsigned char*)d_ws, rbng, rbnb, rw3, rb3,
                                  dbng, dbnb, dw2, db2, (float*)d_out);
}

// Round 2
// 6043.406 us; speedup vs baseline: 1.2064x; 1.2064x over previous
//
#include <hip/hip_runtime.h>
#include <hip/hip_bf16.h>
#include <math.h>

#define Bb   128
#define Ss   512
#define Ff   64
#define Hh   512
#define NGc  2053          // 4*H + 5
#define Kk   576           // F + H
#define NWG  32
#define NT   80            // padded gate cols per WG (64 gates + 5 d + pad)
#define BST  584           // padded k-stride (shorts) for LDS weights

// workspace layout (bytes)
#define OFF_ARR   0                        // 32 x 128B arrival flags
#define OFF_HB    4096                     // 2 x B*H bf16 ping-pong (131072 each)
#define OFF_HFIN  266240                   // B*H fp32
#define OFF_CFIN  528384                   // 5 x B*H fp32
#define OFF_R1    1839104                  // 128x256 fp32
#define OFF_R2    1970176                  // 128x128 fp32
#define OFF_Y1    2035712                  // 5 x 128x256 fp32

typedef __attribute__((ext_vector_type(8))) short short8;
typedef __attribute__((ext_vector_type(4))) float f32x4;

__device__ __forceinline__ short f2bf(float f) {
    union { float f; unsigned u; } v; v.f = f;
    unsigned r = v.u + 0x7fffu + ((v.u >> 16) & 1u);
    return (short)(r >> 16);
}

// ---- distributed sense barrier: per-WG flag on its own 128B line ----
__device__ __forceinline__ void bar_arrive(unsigned* arr, int wg, unsigned val) {
    __syncthreads();                 // all threads' h-stores issued
    if (threadIdx.x == 0) {
        __threadfence();             // release: h visible before flag
        __hip_atomic_store(&arr[wg * 32], val, __ATOMIC_RELEASE, __HIP_MEMORY_SCOPE_AGENT);
    }
}

__device__ __forceinline__ void bar_wait(unsigned* arr, unsigned tgt) {
    if (threadIdx.x < 64) {
        const int  l    = threadIdx.x;
        const bool mine = l < NWG;
        for (;;) {
            unsigned v = mine ? __hip_atomic_load(&arr[l * 32], __ATOMIC_ACQUIRE,
                                                  __HIP_MEMORY_SCOPE_AGENT)
                              : 0xFFFFFFFFu;
            if (__all((int)(v >= tgt))) break;
            __builtin_amdgcn_s_sleep(2);
        }
        __threadfence();             // acquire chain for whole WG via syncthreads
    }
    __syncthreads();
}

__global__ __launch_bounds__(256, 1) void mclstm_main(
    const float* __restrict__ xin, const float* __restrict__ Wm,
    const float* __restrict__ Um,  const float* __restrict__ k1,
    const float* __restrict__ bias, const float* __restrict__ bias1,
    float* __restrict__ out, unsigned char* __restrict__ ws)
{
    __shared__ __align__(16) short sB[NT * BST];   // 91 KB: Bt[n][k] bf16
    __shared__ float sD[128 * 8];                  // d-gate dump / d values

    const int tid  = threadIdx.x;
    const int wg   = blockIdx.x;
    const int lane = tid & 63;
    const int wave = tid >> 6;
    const int j0   = wg * 16;

    unsigned* arr  = (unsigned*)(ws + OFF_ARR);
    short*    hbuf = (short*)(ws + OFF_HB);
    float*    hfin = (float*)(ws + OFF_HFIN);
    float*    cfin = (float*)(ws + OFF_CFIN);

    // ---- stage weights into LDS: sB[n*BST + k], n in [0,80) ----
    for (int e = tid; e < NT * Kk; e += 256) {
        int n = e % NT, k = e / NT;
        int col = -1;
        if (n < 64)      col = (n >> 4) * Hh + j0 + (n & 15);
        else if (n < 69) col = 4 * Hh + (n - 64);
        float v = 0.f;
        if (col >= 0) v = (k < Ff) ? Wm[(size_t)k * NGc + col]
                                   : Um[(size_t)(k - Ff) * NGc + col];
        sB[n * BST + k] = f2bf(v);
    }

    const int col16 = lane & 15;
    const int quad  = lane >> 4;
    const int kgrp  = quad * 8;

    // bias per n-tile (col = col16)
    float biasreg[5];
#pragma unroll
    for (int nt = 0; nt < 5; ++nt) {
        int col;
        if (nt < 4) col = nt * Hh + j0 + col16;
        else        col = (col16 < 5) ? (4 * Hh + col16) : -1;
        biasreg[nt] = (col >= 0) ? bias[col] : 0.f;
    }

    // per-lane elementwise constants: lane owns hidden unit u = col16
    const float s1v = bias1[j0 + col16];
    const float s2v = bias1[Hh + j0 + col16];
    float kv[5];
#pragma unroll
    for (int g = 0; g < 5; ++g) kv[g] = k1[g * Hh + j0 + col16];
    float cp[2][4] = {{0,0,0,0},{0,0,0,0}};     // c-state for lane's 8 rows

    const int row0 = wave * 32 + col16;         // m-tile 0 row (A-frag)
    const int row1 = wave * 32 + 16 + col16;    // m-tile 1 row

    __syncthreads();

    for (int t = 0; t < Ss; ++t) {
        const short* hcur  = hbuf + (size_t)(t & 1) * (Bb * Hh);
        short*       hnext = hbuf + (size_t)((t + 1) & 1) * (Bb * Hh);

        // ---- x_t loads (independent of barrier) ----
        short8 Ax[2][2];
#pragma unroll
        for (int k0 = 0; k0 < 2; ++k0) {
            int kb = k0 * 32 + kgrp;
            const float* p0 = xin + ((size_t)row0 * Ss + t) * Ff + kb;
            const float* p1 = xin + ((size_t)row1 * Ss + t) * Ff + kb;
            f32x4 f00 = *(const f32x4*)(p0);
            f32x4 f01 = *(const f32x4*)(p0 + 4);
            f32x4 f10 = *(const f32x4*)(p1);
            f32x4 f11 = *(const f32x4*)(p1 + 4);
#pragma unroll
            for (int j = 0; j < 4; ++j) {
                Ax[k0][0][j]     = f2bf(f00[j]); Ax[k0][0][4 + j] = f2bf(f01[j]);
                Ax[k0][1][j]     = f2bf(f10[j]); Ax[k0][1][4 + j] = f2bf(f11[j]);
            }
        }

        // ---- wait for step-t h to be globally visible ----
        bar_wait(arr, (unsigned)t);

        // ---- issue ALL h-fragment loads up front (32 x 16B, deep in flight) ----
        short8 Ah[16][2];
#pragma unroll
        for (int k0 = 0; k0 < 16; ++k0) {
            int kb = k0 * 32 + kgrp;
            Ah[k0][0] = *(const short8*)(hcur + (size_t)row0 * Hh + kb);
            Ah[k0][1] = *(const short8*)(hcur + (size_t)row1 * Hh + kb);
        }

        // ---- accumulators ----
        f32x4 acc[5][2];
#pragma unroll
        for (int nt = 0; nt < 5; ++nt)
#pragma unroll
            for (int mt = 0; mt < 2; ++mt) {
                f32x4 z = {biasreg[nt], biasreg[nt], biasreg[nt], biasreg[nt]};
                acc[nt][mt] = z;
            }

        // ---- x part (k = 0..63) while h loads are in flight ----
#pragma unroll
        for (int k0 = 0; k0 < 2; ++k0) {
            int kb = k0 * 32 + kgrp;
#pragma unroll
            for (int nt = 0; nt < 5; ++nt) {
                short8 b = *(const short8*)(sB + (nt * 16 + col16) * BST + kb);
                acc[nt][0] = __builtin_amdgcn_mfma_f32_16x16x32_bf16(Ax[k0][0], b, acc[nt][0], 0, 0, 0);
                acc[nt][1] = __builtin_amdgcn_mfma_f32_16x16x32_bf16(Ax[k0][1], b, acc[nt][1], 0, 0, 0);
            }
        }
        // ---- h part (k = 64..575) ----
#pragma unroll
        for (int k0 = 0; k0 < 16; ++k0) {
            int kb = 64 + k0 * 32 + kgrp;
#pragma unroll
            for (int nt = 0; nt < 5; ++nt) {
                short8 b = *(const short8*)(sB + (nt * 16 + col16) * BST + kb);
                acc[nt][0] = __builtin_amdgcn_mfma_f32_16x16x32_bf16(Ah[k0][0], b, acc[nt][0], 0, 0, 0);
                acc[nt][1] = __builtin_amdgcn_mfma_f32_16x16x32_bf16(Ah[k0][1], b, acc[nt][1], 0, 0, 0);
            }
        }

        // ---- d gate: dump cols 0..4 (tile 4), softmax(tanh(.)) per row ----
        if (col16 < 5) {
#pragma unroll
            for (int mt = 0; mt < 2; ++mt)
#pragma unroll
                for (int j = 0; j < 4; ++j)
                    sD[(wave * 32 + mt * 16 + quad * 4 + j) * 8 + col16] = acc[4][mt][j];
        }
        __syncthreads();
        if (tid < 128) {
            int r = tid;
            float v[5], mx = -1e30f;
#pragma unroll
            for (int c = 0; c < 5; ++c) { v[c] = tanhf(sD[r * 8 + c]); mx = fmaxf(mx, v[c]); }
            float s = 0.f;
#pragma unroll
            for (int c = 0; c < 5; ++c) { v[c] = __expf(v[c] - mx); s += v[c]; }
            float inv = 1.f / s;
#pragma unroll
            for (int c = 0; c < 5; ++c) sD[r * 8 + c] = v[c] * inv;
            if (t == Ss - 1 && wg == 0) {
#pragma unroll
                for (int c = 0; c < 5; ++c) out[1408 + r * 5 + c] = v[c] * inv;
            }
        }
        __syncthreads();

        // ---- cell update: i/f/g/o are tiles 0..3, same lane, no shuffles ----
#pragma unroll
        for (int mt = 0; mt < 2; ++mt) {
#pragma unroll
            for (int j = 0; j < 4; ++j) {
                int r = wave * 32 + mt * 16 + quad * 4 + j;
                float i_ = 1.f / (1.f + __expf(-acc[0][mt][j]));
                float f_ = 1.f / (1.f + __expf(-acc[1][mt][j]));
                float g_ = tanhf(acc[2][mt][j]);
                float o_ = 1.f / (1.f + __expf(-acc[3][mt][j]));
                float c1v = tanhf(g_);
                float c5v = cp[mt][j];
                float c3v = f_ * c5v + i_ * g_;
                float c2v = s2v * c3v + (1.f - s2v) * c1v;
                float c4v = s1v * c3v + (1.f - s1v) * c5v;
                const float* dr = sD + r * 8;
                float cn = dr[0] * kv[0] * c1v + dr[1] * kv[1] * c2v + dr[2] * kv[2] * c3v
                         + dr[3] * kv[3] * c4v + dr[4] * kv[4] * c5v;
                float hn = o_ * tanhf(cn);
                cp[mt][j] = cn;
                size_t off = (size_t)r * Hh + j0 + col16;
                hnext[off] = f2bf(hn);
                if (t == Ss - 1) {
                    hfin[off] = hn;
                    cfin[0 * Bb * Hh + off] = c1v;
                    cfin[1 * Bb * Hh + off] = c2v;
                    cfin[2 * Bb * Hh + off] = c3v;
                    cfin[3 * Bb * Hh + off] = c4v;
                    cfin[4 * Bb * Hh + off] = c5v;
                }
            }
        }
        if (t < Ss - 1) bar_arrive(arr, wg, (unsigned)(t + 1));
    }
}

// ---- heads: stage A: r1 = relu(h@rw1+rb1); y1[hd] = relu(c_hd@dw1+db1) ----
__global__ __launch_bounds__(256) void stageA(const unsigned char* __restrict__ ws,
    const float* __restrict__ rw1, const float* __restrict__ rb1,
    const float* __restrict__ dw1, const float* __restrict__ db1)
{
    __shared__ float sW[512 * 17];
    const int tid = threadIdx.x;
    const int blk = blockIdx.x;
    const float* hfin = (const float*)(ws + OFF_HFIN);
    const float* cfin = (const float*)(ws + OFF_CFIN);
    float* r1 = (float*)(ws + OFF_R1);
    float* y1 = (float*)(ws + OFF_Y1);

    const float* src; const float* Wm; const float* bv; float* dst; int cblk;
    if (blk < 16) { src = hfin; Wm = rw1; bv = rb1; dst = r1; cblk = blk; }
    else {
        int hd = (blk - 16) >> 4; cblk = (blk - 16) & 15;
        src = cfin + (size_t)hd * Bb * Hh; Wm = dw1; bv = db1;
        dst = y1 + (size_t)hd * Bb * 256;
    }
    for (int e = tid; e < 512 * 16; e += 256) {
        int k = e >> 4, c = e & 15;
        sW[k * 17 + c] = Wm[(size_t)k * 256 + cblk * 16 + c];
    }
    __syncthreads();
    for (int e = tid; e < 128 * 16; e += 256) {
        int r = e >> 4, c = e & 15;
        float a = bv[cblk * 16 + c];
        const float* sp = src + (size_t)r * 512;
        for (int k = 0; k < 512; k += 4) {
            f32x4 h4 = *(const f32x4*)(sp + k);
            a += h4[0] * sW[(k + 0) * 17 + c] + h4[1] * sW[(k + 1) * 17 + c]
               + h4[2] * sW[(k + 2) * 17 + c] + h4[3] * sW[(k + 3) * 17 + c];
        }
        dst[(size_t)r * 256 + cblk * 16 + c] = fmaxf(a, 0.f);
    }
}

// ---- stage B: r2 = relu(r1@rw2+rb2) ----
__global__ __launch_bounds__(256) void stageB(const unsigned char* __restrict__ ws,
    const float* __restrict__ rw2, const float* __restrict__ rb2)
{
    __shared__ float sW[256 * 17];
    const int tid = threadIdx.x;
    const int cblk = blockIdx.x;
    const float* r1 = (const float*)(ws + OFF_R1);
    float* r2 = (float*)(ws + OFF_R2);
    for (int e = tid; e < 256 * 16; e += 256) {
        int k = e >> 4, c = e & 15;
        sW[k * 17 + c] = rw2[(size_t)k * 128 + cblk * 16 + c];
    }
    __syncthreads();
    for (int e = tid; e < 128 * 16; e += 256) {
        int r = e >> 4, c = e & 15;
        float a = rb2[cblk * 16 + c];
        const float* sp = r1 + (size_t)r * 256;
        for (int k = 0; k < 256; k += 4) {
            f32x4 h4 = *(const f32x4*)(sp + k);
            a += h4[0] * sW[(k + 0) * 17 + c] + h4[1] * sW[(k + 1) * 17 + c]
               + h4[2] * sW[(k + 2) * 17 + c] + h4[3] * sW[(k + 3) * 17 + c];
        }
        r2[(size_t)r * 128 + cblk * 16 + c] = fmaxf(a, 0.f);
    }
}

// ---- stage C: BN + final projections + log_softmax ----
__global__ __launch_bounds__(256) void stageC(const unsigned char* __restrict__ ws,
    const float* __restrict__ rbng, const float* __restrict__ rbnb,
    const float* __restrict__ rw3,  const float* __restrict__ rb3,
    const float* __restrict__ dbng, const float* __restrict__ dbnb,
    const float* __restrict__ dw2,  const float* __restrict__ db2,
    float* __restrict__ out)
{
    __shared__ float sc[256], sh[256];
    const int tid = threadIdx.x;
    const int blk = blockIdx.x;
    const float* r2 = (const float*)(ws + OFF_R2);
    const float* y1 = (const float*)(ws + OFF_Y1);
    if (blk == 0) {
        if (tid < 128) {
            int c = tid; float s = 0.f, s2 = 0.f;
            for (int r = 0; r < 128; ++r) { float x = r2[r * 128 + c]; s += x; s2 += x * x; }
            float m = s * (1.f / 128.f), v = s2 * (1.f / 128.f) - m * m;
            float sca = rbng[c] * rsqrtf(v + 1e-5f);
            sc[c] = sca; sh[c] = rbnb[c] - m * sca;
        }
        __syncthreads();
        if (tid < 128) {
            int r = tid; float a = rb3[0];
            for (int c = 0; c < 128; ++c)
                a += (r2[r * 128 + c] * sc[c] + sh[c]) * rw3[c];
            out[r] = a;
        }
    } else {
        int hd = blk - 1;
        const float* y = y1 + (size_t)hd * 128 * 256;
        {
            int c = tid; float s = 0.f, s2 = 0.f;
            for (int r = 0; r < 128; ++r) { float x = y[r * 256 + c]; s += x; s2 += x * x; }
            float m = s * (1.f / 128.f), v = s2 * (1.f / 128.f) - m * m;
            float sca = dbng[c] * rsqrtf(v + 1e-5f);
            sc[c] = sca; sh[c] = dbnb[c] - m * sca;
        }
        __syncthreads();
        if (tid < 128) {
            int r = tid;
            float z0 = db2[0], z1 = db2[1];
            for (int c = 0; c < 256; ++c) {
                float yn = y[r * 256 + c] * sc[c] + sh[c];
                z0 += yn * dw2[c * 2 + 0];
                z1 += yn * dw2[c * 2 + 1];
            }
            float mx = fmaxf(z0, z1);
            float ls = mx + logf(__expf(z0 - mx) + __expf(z1 - mx));
            out[128 + hd * 256 + r * 2 + 0] = z0 - ls;
            out[128 + hd * 256 + r * 2 + 1] = z1 - ls;
        }
    }
}

extern "C" void kernel_launch(void* const* d_in, const int* in_sizes, int n_in,
                              void* d_out, int out_size, void* d_ws, size_t ws_size,
                              hipStream_t stream) {
    const float* x    = (const float*)d_in[0];
    const float* Wm   = (const float*)d_in[1];
    const float* Um   = (const float*)d_in[2];
    const float* k1   = (const float*)d_in[3];
    const float* bias = (const float*)d_in[4];
    const float* b1   = (const float*)d_in[5];
    const float* rw1  = (const float*)d_in[6];
    const float* rb1  = (const float*)d_in[7];
    const float* rw2  = (const float*)d_in[8];
    const float* rb2  = (const float*)d_in[9];
    const float* rbng = (const float*)d_in[10];
    const float* rbnb = (const float*)d_in[11];
    const float* rw3  = (const float*)d_in[12];
    const float* rb3  = (const float*)d_in[13];
    const float* dw1  = (const float*)d_in[14];
    const float* db1  = (const float*)d_in[15];
    const float* dbng = (const float*)d_in[16];
    const float* dbnb = (const float*)d_in[17];
    const float* dw2  = (const float*)d_in[18];
    const float* db2  = (const float*)d_in[19];
    (void)in_sizes; (void)n_in; (void)out_size; (void)ws_size;

    // zero arrival flags + h ping buffer 0
    hipMemsetAsync(d_ws, 0, OFF_HB + Bb * Hh * 2, stream);

    mclstm_main<<<NWG, 256, 0, stream>>>(x, Wm, Um, k1, bias, b1,
                                         (float*)d_out, (unsigned char*)d_ws);
    stageA<<<96, 256, 0, stream>>>((const unsigned char*)d_ws, rw1, rb1, dw1, db1);
    stageB<<<8, 256, 0, stream>>>((const unsigned char*)d_ws, rw2, rb2);
    stageC<<<6, 256, 0, stream>>>((const unsigned char*)d_ws, rbng, rbnb, rw3, rb3,
                                  dbng, dbnb, dw2, db2, (float*)d_out);
}